// Round 2
// baseline (6313.789 us; speedup 1.0000x reference)
//
#include <hip/hip_runtime.h>
#include <math.h>

#define N_EMBD 768
#define T_SEQ  1024
#define BATCH  8
#define NHEAD  12
#define HD     64
#define EPS    1e-5f
#define M_TOK  (BATCH * T_SEQ)   // 8192

// ---------------- LayerNorm: one block per token row (768 floats) ----------------
__global__ __launch_bounds__(256) void ln_kernel(const float* __restrict__ x,
                                                 const float* __restrict__ g,
                                                 const float* __restrict__ b,
                                                 float* __restrict__ out) {
    int row = blockIdx.x;
    int tid = threadIdx.x;
    const float* xr = x + (size_t)row * N_EMBD;
    float v0 = xr[tid], v1 = xr[tid + 256], v2 = xr[tid + 512];
    float s1 = v0 + v1 + v2;
    float s2 = v0 * v0 + v1 * v1 + v2 * v2;
    __shared__ float red1[4], red2[4];
#pragma unroll
    for (int o = 32; o > 0; o >>= 1) {
        s1 += __shfl_down(s1, o);
        s2 += __shfl_down(s2, o);
    }
    if ((tid & 63) == 0) { red1[tid >> 6] = s1; red2[tid >> 6] = s2; }
    __syncthreads();
    float mean = (red1[0] + red1[1] + red1[2] + red1[3]) * (1.0f / N_EMBD);
    float ms   = (red2[0] + red2[1] + red2[2] + red2[3]) * (1.0f / N_EMBD);
    float rs = rsqrtf(ms - mean * mean + EPS);
    float* orow = out + (size_t)row * N_EMBD;
    orow[tid]       = (v0 - mean) * rs * g[tid]       + b[tid];
    orow[tid + 256] = (v1 - mean) * rs * g[tid + 256] + b[tid + 256];
    orow[tid + 512] = (v2 - mean) * rs * g[tid + 512] + b[tid + 512];
}

// ---------------- fp32 tiled GEMM: out[M,N] = A[M,K] @ W[K,N] + bias (+epilogue) ----------------
// mode: 0 = bias only, 1 = bias + tanh-gelu, 2 = bias + residual add
#define BM 64
#define BN 64
#define BK 32
__global__ __launch_bounds__(256) void gemm_f32(const float* __restrict__ A,
                                                const float* __restrict__ W,
                                                const float* __restrict__ bias,
                                                const float* __restrict__ res,
                                                float* __restrict__ out,
                                                int M, int N, int K, int mode) {
    __shared__ float As[BK][BM + 1];  // +1 pad: transpose-store bank spread
    __shared__ float Bs[BK][BN];
    int tid = threadIdx.x;
    int bm = blockIdx.y * BM;
    int bn = blockIdx.x * BN;
    int tx = tid & 15, ty = tid >> 4;
    float acc[4][4] = {};
    for (int k0 = 0; k0 < K; k0 += BK) {
#pragma unroll
        for (int i = 0; i < 2; i++) {
            int f = tid + i * 256;
            // A tile 64x32: 512 float4s
            int r = f >> 3;
            int c = (f & 7) << 2;
            float4 va = *(const float4*)&A[(size_t)(bm + r) * K + k0 + c];
            As[c + 0][r] = va.x; As[c + 1][r] = va.y;
            As[c + 2][r] = va.z; As[c + 3][r] = va.w;
            // B tile 32x64: 512 float4s
            int rb = f >> 4;
            int cb = (f & 15) << 2;
            *(float4*)&Bs[rb][cb] = *(const float4*)&W[(size_t)(k0 + rb) * N + bn + cb];
        }
        __syncthreads();
#pragma unroll
        for (int k = 0; k < BK; k++) {
            float4 a = *(const float4*)&As[k][ty << 2];
            float4 bv = *(const float4*)&Bs[k][tx << 2];
            float av[4] = {a.x, a.y, a.z, a.w};
            float bw[4] = {bv.x, bv.y, bv.z, bv.w};
#pragma unroll
            for (int i = 0; i < 4; i++)
#pragma unroll
                for (int j = 0; j < 4; j++)
                    acc[i][j] = fmaf(av[i], bw[j], acc[i][j]);
        }
        __syncthreads();
    }
#pragma unroll
    for (int i = 0; i < 4; i++) {
        int rr = bm + (ty << 2) + i;
#pragma unroll
        for (int j = 0; j < 4; j++) {
            int cc = bn + (tx << 2) + j;
            float v = acc[i][j] + bias[cc];
            if (mode == 1) {
                float u = v + 0.044715f * v * v * v;
                v = 0.5f * v * (1.0f + tanhf(0.7978845608028654f * u));
            } else if (mode == 2) {
                v += res[(size_t)rr * N + cc];
            }
            out[(size_t)rr * N + cc] = v;
        }
    }
}

// ---------------- causal attention, one block per (b,h,t) row ----------------
// qkv layout: [B, T, 3C]; q at col h*64, k at 768+h*64, v at 1536+h*64
__global__ __launch_bounds__(256) void attn_kernel(const float* __restrict__ qkv,
                                                   float* __restrict__ out) {
    int t = blockIdx.x, h = blockIdx.y, b = blockIdx.z;
    int tid = threadIdx.x;
    __shared__ float sq[HD];
    __shared__ float sp[T_SEQ];
    __shared__ float red[8];
    __shared__ float part[4][HD];
    const size_t RS = 3 * N_EMBD;
    const float* base = qkv + (size_t)b * T_SEQ * RS;
    if (tid < HD) sq[tid] = base[(size_t)t * RS + h * HD + tid];
    __syncthreads();
    int nS = t + 1;
    // scores (causal: s <= t), unscaled per reference
    for (int s = tid; s < nS; s += 256) {
        const float* kr = base + (size_t)s * RS + N_EMBD + h * HD;
        float acc = 0.f;
#pragma unroll
        for (int d = 0; d < HD; d += 4) {
            float4 kv = *(const float4*)&kr[d];
            acc = fmaf(sq[d], kv.x, acc);
            acc = fmaf(sq[d + 1], kv.y, acc);
            acc = fmaf(sq[d + 2], kv.z, acc);
            acc = fmaf(sq[d + 3], kv.w, acc);
        }
        sp[s] = acc;
    }
    __syncthreads();
    // row max
    float m = -1e30f;
    for (int s = tid; s < nS; s += 256) m = fmaxf(m, sp[s]);
#pragma unroll
    for (int o = 32; o > 0; o >>= 1) m = fmaxf(m, __shfl_down(m, o));
    if ((tid & 63) == 0) red[tid >> 6] = m;
    __syncthreads();
    m = fmaxf(fmaxf(red[0], red[1]), fmaxf(red[2], red[3]));
    // exp + sum
    float lsum = 0.f;
    for (int s = tid; s < nS; s += 256) {
        float e = __expf(sp[s] - m);
        sp[s] = e;
        lsum += e;
    }
    __syncthreads();
#pragma unroll
    for (int o = 32; o > 0; o >>= 1) lsum += __shfl_down(lsum, o);
    if ((tid & 63) == 0) red[4 + (tid >> 6)] = lsum;
    __syncthreads();
    float denom = red[4] + red[5] + red[6] + red[7];
    // PV: 64 d-lanes x 4 s-groups
    int d = tid & 63, grp = tid >> 6;
    float acc = 0.f;
    for (int s = grp; s < nS; s += 4)
        acc = fmaf(sp[s], base[(size_t)s * RS + 2 * N_EMBD + h * HD + d], acc);
    part[grp][d] = acc;
    __syncthreads();
    if (grp == 0) {
        float o4 = (part[0][d] + part[1][d] + part[2][d] + part[3][d]) / denom;
        out[((size_t)(b * T_SEQ + t)) * N_EMBD + h * HD + d] = o4;
    }
}

extern "C" void kernel_launch(void* const* d_in, const int* in_sizes, int n_in,
                              void* d_out, int out_size, void* d_ws, size_t ws_size,
                              hipStream_t stream) {
    (void)in_sizes; (void)n_in; (void)out_size; (void)ws_size;
    const float* x      = (const float*)d_in[0];
    const float* ln1_g  = (const float*)d_in[1];
    const float* ln1_b  = (const float*)d_in[2];
    const float* w_attn = (const float*)d_in[3];
    const float* b_attn = (const float*)d_in[4];
    const float* w_proj = (const float*)d_in[5];
    const float* b_proj = (const float*)d_in[6];
    const float* ln2_g  = (const float*)d_in[7];
    const float* ln2_b  = (const float*)d_in[8];
    const float* w_fc   = (const float*)d_in[9];
    const float* b_fc   = (const float*)d_in[10];
    const float* w_fc2  = (const float*)d_in[11];
    const float* b_fc2  = (const float*)d_in[12];
    float* out = (float*)d_out;
    float* ws  = (float*)d_ws;

    // ws layout (floats), 126 MB total with reuse:
    //   buf0 = ws          : 6.29M  (LN1 out -> attn out -> LN2 out)
    //   buf1 = ws + 6.29M  : 25.2M  (qkv [8192,2304] -> fc out [8192,3072])
    float* buf0 = ws;
    float* buf1 = ws + (size_t)M_TOK * N_EMBD;

    // 1. h = LN1(x)
    ln_kernel<<<M_TOK, 256, 0, stream>>>(x, ln1_g, ln1_b, buf0);
    // 2. qkv = h @ w_attn + b_attn       [8192, 2304]
    gemm_f32<<<dim3(3 * N_EMBD / BN, M_TOK / BM), 256, 0, stream>>>(
        buf0, w_attn, b_attn, nullptr, buf1, M_TOK, 3 * N_EMBD, N_EMBD, 0);
    // 3. attn = softmax(causal(q k^T)) v  -> buf0 [8192, 768]
    attn_kernel<<<dim3(T_SEQ, NHEAD, BATCH), 256, 0, stream>>>(buf1, buf0);
    // 4. x1 = x + attn @ w_proj + b_proj  -> d_out
    gemm_f32<<<dim3(N_EMBD / BN, M_TOK / BM), 256, 0, stream>>>(
        buf0, w_proj, b_proj, x, out, M_TOK, N_EMBD, N_EMBD, 2);
    // 5. h2 = LN2(x1) -> buf0
    ln_kernel<<<M_TOK, 256, 0, stream>>>(out, ln2_g, ln2_b, buf0);
    // 6. g = gelu(h2 @ w_fc + b_fc) -> buf1 [8192, 3072]
    gemm_f32<<<dim3(4 * N_EMBD / BN, M_TOK / BM), 256, 0, stream>>>(
        buf0, w_fc, b_fc, nullptr, buf1, M_TOK, 4 * N_EMBD, N_EMBD, 1);
    // 7. out = x1 + g @ w_fc2 + b_fc2  (in-place residual from d_out)
    gemm_f32<<<dim3(N_EMBD / BN, M_TOK / BM), 256, 0, stream>>>(
        buf1, w_fc2, b_fc2, out, out, M_TOK, N_EMBD, 4 * N_EMBD, 2);
}

// Round 3
// 473.350 us; speedup vs baseline: 13.3385x; 13.3385x over previous
//
#include <hip/hip_runtime.h>
#include <math.h>

#define N_EMBD 768
#define T_SEQ  1024
#define BATCH  8
#define NHEAD  12
#define HD     64
#define EPS    1e-5f
#define M_TOK  (BATCH * T_SEQ)   // 8192

typedef unsigned short u16;
typedef __attribute__((ext_vector_type(8))) short          s16x8;
typedef __attribute__((ext_vector_type(8))) unsigned short u16x8;
typedef __attribute__((ext_vector_type(4))) float          f32x4;

// fp32 -> bf16 round-to-nearest-even
__device__ __forceinline__ u16 f2bf(float f) {
    unsigned int u = __float_as_uint(f);
    u += 0x7fffu + ((u >> 16) & 1u);
    return (u16)(u >> 16);
}
__device__ __forceinline__ float bf2f(u16 h) {
    return __uint_as_float(((unsigned int)h) << 16);
}

// ---------------- weight convert + transpose: fp32 [R][C] -> bf16 [C][R] ----------------
__global__ __launch_bounds__(256) void wconv(const float* __restrict__ in,
                                             u16* __restrict__ out, int R, int C) {
    __shared__ float tile[64][65];
    int t = threadIdx.x;
    int r0 = blockIdx.y * 64, c0 = blockIdx.x * 64;
    int rl = t >> 4, c4 = (t & 15) * 4;
#pragma unroll
    for (int i = 0; i < 4; i++) {
        float4 v = *(const float4*)(in + (size_t)(r0 + rl + i * 16) * C + c0 + c4);
        tile[rl + i * 16][c4 + 0] = v.x;
        tile[rl + i * 16][c4 + 1] = v.y;
        tile[rl + i * 16][c4 + 2] = v.z;
        tile[rl + i * 16][c4 + 3] = v.w;
    }
    __syncthreads();
#pragma unroll
    for (int i = 0; i < 4; i++) {
        int crow = rl + i * 16;  // out row = original column index (c0+crow)
        ushort4 s4;
        s4.x = f2bf(tile[c4 + 0][crow]);
        s4.y = f2bf(tile[c4 + 1][crow]);
        s4.z = f2bf(tile[c4 + 2][crow]);
        s4.w = f2bf(tile[c4 + 3][crow]);
        *(ushort4*)(out + (size_t)(c0 + crow) * R + r0 + c4) = s4;
    }
}

// ---------------- LayerNorm fp32 in -> bf16 out ----------------
__global__ __launch_bounds__(256) void ln_bf16(const float* __restrict__ x,
                                               const float* __restrict__ g,
                                               const float* __restrict__ b,
                                               u16* __restrict__ out) {
    int row = blockIdx.x;
    int tid = threadIdx.x;
    const float* xr = x + (size_t)row * N_EMBD;
    float v0 = xr[tid], v1 = xr[tid + 256], v2 = xr[tid + 512];
    float s1 = v0 + v1 + v2;
    float s2 = v0 * v0 + v1 * v1 + v2 * v2;
    __shared__ float red1[4], red2[4];
#pragma unroll
    for (int o = 32; o > 0; o >>= 1) {
        s1 += __shfl_down(s1, o);
        s2 += __shfl_down(s2, o);
    }
    if ((tid & 63) == 0) { red1[tid >> 6] = s1; red2[tid >> 6] = s2; }
    __syncthreads();
    float mean = (red1[0] + red1[1] + red1[2] + red1[3]) * (1.0f / N_EMBD);
    float ms   = (red2[0] + red2[1] + red2[2] + red2[3]) * (1.0f / N_EMBD);
    float rs = rsqrtf(ms - mean * mean + EPS);
    u16* orow = out + (size_t)row * N_EMBD;
    orow[tid]       = f2bf((v0 - mean) * rs * g[tid]       + b[tid]);
    orow[tid + 256] = f2bf((v1 - mean) * rs * g[tid + 256] + b[tid + 256]);
    orow[tid + 512] = f2bf((v2 - mean) * rs * g[tid + 512] + b[tid + 512]);
}

// ---------------- bf16 MFMA GEMM: C[M,N] = A[M,K] @ Bt[N,K]^T + bias (+epilogue) -------
// MODE 0: out bf16 = acc + bias
// MODE 1: out bf16 = gelu(acc + bias)
// MODE 2: out fp32 = acc + bias + res
template <int MODE>
__global__ __launch_bounds__(256) void gemm_bf16(const u16* __restrict__ A,
                                                 const u16* __restrict__ Bt,
                                                 const float* __restrict__ bias,
                                                 const float* __restrict__ res,
                                                 void* __restrict__ outp,
                                                 int M, int N, int K) {
    __shared__ u16 As[128][72];  // pitch 144B -> 2-way bank aliasing (free)
    __shared__ u16 Bs[128][72];
    int tid = threadIdx.x;
    int l = tid & 63, w = tid >> 6;
    int lr = l & 15, lg = l >> 4;
    int bm = blockIdx.y * 128, bn = blockIdx.x * 128;
    int wr = (w >> 1) * 64, wc = (w & 1) * 64;
    f32x4 acc[4][4] = {};
    for (int k0 = 0; k0 < K; k0 += 64) {
        __syncthreads();
#pragma unroll
        for (int i = 0; i < 4; i++) {
            int c = i * 256 + tid;
            int row = c >> 3, k8 = (c & 7) * 8;
            *(u16x8*)&As[row][k8] = *(const u16x8*)(A + (size_t)(bm + row) * K + k0 + k8);
            *(u16x8*)&Bs[row][k8] = *(const u16x8*)(Bt + (size_t)(bn + row) * K + k0 + k8);
        }
        __syncthreads();
#pragma unroll
        for (int kk = 0; kk < 2; kk++) {
            s16x8 af[4], bf[4];
#pragma unroll
            for (int i = 0; i < 4; i++) {
                af[i] = *(const s16x8*)&As[wr + i * 16 + lr][kk * 32 + lg * 8];
                bf[i] = *(const s16x8*)&Bs[wc + i * 16 + lr][kk * 32 + lg * 8];
            }
#pragma unroll
            for (int mi = 0; mi < 4; mi++)
#pragma unroll
                for (int nj = 0; nj < 4; nj++)
                    acc[mi][nj] = __builtin_amdgcn_mfma_f32_16x16x32_bf16(
                        af[mi], bf[nj], acc[mi][nj], 0, 0, 0);
        }
    }
#pragma unroll
    for (int mi = 0; mi < 4; mi++)
#pragma unroll
        for (int nj = 0; nj < 4; nj++)
#pragma unroll
            for (int r = 0; r < 4; r++) {
                int row = bm + wr + mi * 16 + lg * 4 + r;
                int col = bn + wc + nj * 16 + lr;
                float v = acc[mi][nj][r] + bias[col];
                if (MODE == 1) {
                    float u = v + 0.044715f * v * v * v;
                    v = 0.5f * v * (1.0f + tanhf(0.7978845608028654f * u));
                }
                if (MODE == 2) {
                    v += res[(size_t)row * N + col];
                    ((float*)outp)[(size_t)row * N + col] = v;
                } else {
                    ((u16*)outp)[(size_t)row * N + col] = f2bf(v);
                }
            }
}

// ---------------- flash attention, bf16 MFMA, causal, UNSCALED ----------------
// qkv bf16 [B,T,3C]; block = (q-tile of 128, head, batch); 4 waves x 32 q-rows
#define QBLK 128
#define SBLK 64
__global__ __launch_bounds__(256) void attn_mfma(const u16* __restrict__ qkv,
                                                 u16* __restrict__ outp) {
    __shared__ u16 Kl[SBLK][72];
    __shared__ u16 Vt[HD][72];     // V transposed: Vt[d][s]
    __shared__ u16 Pl[4][32][72];  // per-wave P tile
    int tid = threadIdx.x;
    int w = tid >> 6, l = tid & 63;
    int lr = l & 15, lg = l >> 4;
    int qt = blockIdx.x, h = blockIdx.y, b = blockIdx.z;
    int q0 = qt * QBLK;
    size_t bbase = (size_t)b * T_SEQ * (3 * N_EMBD);

    // Q fragments in registers (A-layout: row=lr, k=lg*8+j)
    s16x8 qf[2][2];
#pragma unroll
    for (int rg = 0; rg < 2; rg++)
#pragma unroll
        for (int kk = 0; kk < 2; kk++) {
            int row = q0 + w * 32 + rg * 16 + lr;
            qf[rg][kk] = *(const s16x8*)(qkv + bbase + (size_t)row * (3 * N_EMBD) +
                                         h * HD + kk * 32 + lg * 8);
        }
    f32x4 oacc[2][4] = {};
    float mrun[2][4], lrun[2][4];
#pragma unroll
    for (int rg = 0; rg < 2; rg++)
#pragma unroll
        for (int r = 0; r < 4; r++) { mrun[rg][r] = -1e30f; lrun[rg][r] = 0.f; }

    int nt = 2 * qt + 2;
    for (int st = 0; st < nt; st++) {
        int s0 = st * SBLK;
        // ---- stage K tile + V^T tile ----
#pragma unroll
        for (int i = 0; i < 2; i++) {
            int c = i * 256 + tid;
            int sr = c >> 3, d0 = (c & 7) * 8;
            size_t rb = bbase + (size_t)(s0 + sr) * (3 * N_EMBD) + h * HD;
            u16x8 kv8 = *(const u16x8*)(qkv + rb + N_EMBD + d0);
            *(u16x8*)&Kl[sr][d0] = kv8;
            u16x8 vv = *(const u16x8*)(qkv + rb + 2 * N_EMBD + d0);
#pragma unroll
            for (int j = 0; j < 8; j++) Vt[d0 + j][sr] = vv[j];
        }
        __syncthreads();
        // ---- S = Q @ K^T ----
        f32x4 sacc[2][4] = {};
#pragma unroll
        for (int kk = 0; kk < 2; kk++) {
            s16x8 kf[4];
#pragma unroll
            for (int nj = 0; nj < 4; nj++)
                kf[nj] = *(const s16x8*)&Kl[nj * 16 + lr][kk * 32 + lg * 8];
#pragma unroll
            for (int rg = 0; rg < 2; rg++)
#pragma unroll
                for (int nj = 0; nj < 4; nj++)
                    sacc[rg][nj] = __builtin_amdgcn_mfma_f32_16x16x32_bf16(
                        qf[rg][kk], kf[nj], sacc[rg][nj], 0, 0, 0);
        }
        // ---- mask + online softmax (fp32) + P -> LDS (bf16) ----
#pragma unroll
        for (int rg = 0; rg < 2; rg++) {
            int qrow0 = q0 + w * 32 + rg * 16 + lg * 4;
            float mx[4];
#pragma unroll
            for (int r = 0; r < 4; r++) {
                int qi = qrow0 + r;
                float mv = -1e30f;
#pragma unroll
                for (int nj = 0; nj < 4; nj++) {
                    int si = s0 + nj * 16 + lr;
                    float v = sacc[rg][nj][r];
                    v = (si <= qi) ? v : -1e30f;
                    sacc[rg][nj][r] = v;
                    mv = fmaxf(mv, v);
                }
                mx[r] = mv;
            }
#pragma unroll
            for (int d = 1; d < 16; d <<= 1)
#pragma unroll
                for (int r = 0; r < 4; r++) mx[r] = fmaxf(mx[r], __shfl_xor(mx[r], d, 64));
            float rs[4];
#pragma unroll
            for (int r = 0; r < 4; r++) {
                float mnew = fmaxf(mrun[rg][r], mx[r]);
                float sc = __expf(mrun[rg][r] - mnew);
                mrun[rg][r] = mnew;
                float sum = 0.f;
#pragma unroll
                for (int nj = 0; nj < 4; nj++) {
                    float p = __expf(sacc[rg][nj][r] - mnew);
                    sacc[rg][nj][r] = p;
                    sum += p;
                }
                rs[r] = sum;
                lrun[rg][r] *= sc;
#pragma unroll
                for (int nj = 0; nj < 4; nj++) oacc[rg][nj][r] *= sc;
            }
#pragma unroll
            for (int d = 1; d < 16; d <<= 1)
#pragma unroll
                for (int r = 0; r < 4; r++) rs[r] += __shfl_xor(rs[r], d, 64);
#pragma unroll
            for (int r = 0; r < 4; r++) lrun[rg][r] += rs[r];
#pragma unroll
            for (int nj = 0; nj < 4; nj++)
#pragma unroll
                for (int r = 0; r < 4; r++)
                    Pl[w][rg * 16 + lg * 4 + r][nj * 16 + lr] = f2bf(sacc[rg][nj][r]);
        }
        __syncthreads();
        // ---- O += P @ V ----
#pragma unroll
        for (int kk = 0; kk < 2; kk++) {
            s16x8 af[2], vf[4];
#pragma unroll
            for (int rg = 0; rg < 2; rg++)
                af[rg] = *(const s16x8*)&Pl[w][rg * 16 + lr][kk * 32 + lg * 8];
#pragma unroll
            for (int nj = 0; nj < 4; nj++)
                vf[nj] = *(const s16x8*)&Vt[nj * 16 + lr][kk * 32 + lg * 8];
#pragma unroll
            for (int rg = 0; rg < 2; rg++)
#pragma unroll
                for (int nj = 0; nj < 4; nj++)
                    oacc[rg][nj] = __builtin_amdgcn_mfma_f32_16x16x32_bf16(
                        af[rg], vf[nj], oacc[rg][nj], 0, 0, 0);
        }
        __syncthreads();
    }
    // ---- write O/l as bf16 ----
#pragma unroll
    for (int rg = 0; rg < 2; rg++)
#pragma unroll
        for (int nj = 0; nj < 4; nj++)
#pragma unroll
            for (int r = 0; r < 4; r++) {
                int row = q0 + w * 32 + rg * 16 + lg * 4 + r;
                float v = oacc[rg][nj][r] / lrun[rg][r];
                outp[(size_t)(b * T_SEQ + row) * N_EMBD + h * HD + nj * 16 + lr] = f2bf(v);
            }
}

extern "C" void kernel_launch(void* const* d_in, const int* in_sizes, int n_in,
                              void* d_out, int out_size, void* d_ws, size_t ws_size,
                              hipStream_t stream) {
    (void)in_sizes; (void)n_in; (void)out_size; (void)ws_size;
    const float* x      = (const float*)d_in[0];
    const float* ln1_g  = (const float*)d_in[1];
    const float* ln1_b  = (const float*)d_in[2];
    const float* w_attn = (const float*)d_in[3];
    const float* b_attn = (const float*)d_in[4];
    const float* w_proj = (const float*)d_in[5];
    const float* b_proj = (const float*)d_in[6];
    const float* ln2_g  = (const float*)d_in[7];
    const float* ln2_b  = (const float*)d_in[8];
    const float* w_fc   = (const float*)d_in[9];
    const float* b_fc   = (const float*)d_in[10];
    const float* w_fc2  = (const float*)d_in[11];
    const float* b_fc2  = (const float*)d_in[12];
    float* out = (float*)d_out;
    u16* ws = (u16*)d_ws;

    // ws layout (u16 elems), ~90 MB total
    u16* wTa  = ws;                                      // [2304,768]
    u16* wTp  = wTa + (size_t)2304 * 768;                // [768,768]
    u16* wTf  = wTp + (size_t)768 * 768;                 // [3072,768]
    u16* wTf2 = wTf + (size_t)3072 * 768;                // [768,3072]
    u16* hbuf = wTf2 + (size_t)768 * 3072;               // [8192,768]  LN out
    u16* abuf = hbuf + (size_t)M_TOK * N_EMBD;           // [8192,768]  attn out
    u16* big  = abuf + (size_t)M_TOK * N_EMBD;           // qkv [8192,2304] / fc out [8192,3072]

    // weight convert+transpose
    wconv<<<dim3(2304 / 64, 768 / 64), 256, 0, stream>>>(w_attn, wTa, 768, 2304);
    wconv<<<dim3(768 / 64, 768 / 64), 256, 0, stream>>>(w_proj, wTp, 768, 768);
    wconv<<<dim3(3072 / 64, 768 / 64), 256, 0, stream>>>(w_fc, wTf, 768, 3072);
    wconv<<<dim3(768 / 64, 3072 / 64), 256, 0, stream>>>(w_fc2, wTf2, 3072, 768);
    // 1. h = LN1(x) -> bf16
    ln_bf16<<<M_TOK, 256, 0, stream>>>(x, ln1_g, ln1_b, hbuf);
    // 2. qkv = h @ w_attn + b_attn -> bf16 [8192,2304]
    gemm_bf16<0><<<dim3(18, 64), 256, 0, stream>>>(hbuf, wTa, b_attn, nullptr, big,
                                                   M_TOK, 3 * N_EMBD, N_EMBD);
    // 3. flash attention -> bf16 [8192,768]
    attn_mfma<<<dim3(T_SEQ / QBLK, NHEAD, BATCH), 256, 0, stream>>>(big, abuf);
    // 4. x1 = x + attn @ w_proj + b_proj -> fp32 d_out
    gemm_bf16<2><<<dim3(6, 64), 256, 0, stream>>>(abuf, wTp, b_proj, x, out,
                                                  M_TOK, N_EMBD, N_EMBD);
    // 5. h2 = LN2(x1) -> bf16
    ln_bf16<<<M_TOK, 256, 0, stream>>>(out, ln2_g, ln2_b, hbuf);
    // 6. g = gelu(h2 @ w_fc + b_fc) -> bf16 [8192,3072]
    gemm_bf16<1><<<dim3(24, 64), 256, 0, stream>>>(hbuf, wTf, b_fc, nullptr, big,
                                                   M_TOK, 4 * N_EMBD, N_EMBD);
    // 7. out = x1 + g @ w_fc2 + b_fc2 -> fp32 d_out (in-place residual)
    gemm_bf16<2><<<dim3(6, 64), 256, 0, stream>>>(big, wTf2, b_fc2, out, out,
                                                  M_TOK, N_EMBD, 4 * N_EMBD);
}

// Round 4
// 456.518 us; speedup vs baseline: 13.8303x; 1.0369x over previous
//
#include <hip/hip_runtime.h>
#include <math.h>

#define N_EMBD 768
#define T_SEQ  1024
#define BATCH  8
#define NHEAD  12
#define HD     64
#define EPS    1e-5f
#define M_TOK  (BATCH * T_SEQ)   // 8192

typedef unsigned short u16;
typedef __attribute__((ext_vector_type(8))) short          s16x8;
typedef __attribute__((ext_vector_type(8))) unsigned short u16x8;
typedef __attribute__((ext_vector_type(4))) float          f32x4;

#define GLDS(gp, lp) \
    __builtin_amdgcn_global_load_lds( \
        (const __attribute__((address_space(1))) void*)(gp), \
        (__attribute__((address_space(3))) void*)(lp), 16, 0, 0)

// fp32 -> bf16 round-to-nearest-even
__device__ __forceinline__ u16 f2bf(float f) {
    unsigned int u = __float_as_uint(f);
    u += 0x7fffu + ((u >> 16) & 1u);
    return (u16)(u >> 16);
}

// ---------------- weight convert + transpose: fp32 [R][C] -> bf16 [C][R] ----------------
__global__ __launch_bounds__(256) void wconv(const float* __restrict__ in,
                                             u16* __restrict__ out, int R, int C) {
    __shared__ float tile[64][65];
    int t = threadIdx.x;
    int r0 = blockIdx.y * 64, c0 = blockIdx.x * 64;
    int rl = t >> 4, c4 = (t & 15) * 4;
#pragma unroll
    for (int i = 0; i < 4; i++) {
        float4 v = *(const float4*)(in + (size_t)(r0 + rl + i * 16) * C + c0 + c4);
        tile[rl + i * 16][c4 + 0] = v.x;
        tile[rl + i * 16][c4 + 1] = v.y;
        tile[rl + i * 16][c4 + 2] = v.z;
        tile[rl + i * 16][c4 + 3] = v.w;
    }
    __syncthreads();
#pragma unroll
    for (int i = 0; i < 4; i++) {
        int crow = rl + i * 16;
        ushort4 s4;
        s4.x = f2bf(tile[c4 + 0][crow]);
        s4.y = f2bf(tile[c4 + 1][crow]);
        s4.z = f2bf(tile[c4 + 2][crow]);
        s4.w = f2bf(tile[c4 + 3][crow]);
        *(ushort4*)(out + (size_t)(c0 + crow) * R + r0 + c4) = s4;
    }
}

// ---------------- LayerNorm fp32 in -> bf16 out ----------------
__global__ __launch_bounds__(256) void ln_bf16(const float* __restrict__ x,
                                               const float* __restrict__ g,
                                               const float* __restrict__ b,
                                               u16* __restrict__ out) {
    int row = blockIdx.x;
    int tid = threadIdx.x;
    const float* xr = x + (size_t)row * N_EMBD;
    float v0 = xr[tid], v1 = xr[tid + 256], v2 = xr[tid + 512];
    float s1 = v0 + v1 + v2;
    float s2 = v0 * v0 + v1 * v1 + v2 * v2;
    __shared__ float red1[4], red2[4];
#pragma unroll
    for (int o = 32; o > 0; o >>= 1) {
        s1 += __shfl_down(s1, o);
        s2 += __shfl_down(s2, o);
    }
    if ((tid & 63) == 0) { red1[tid >> 6] = s1; red2[tid >> 6] = s2; }
    __syncthreads();
    float mean = (red1[0] + red1[1] + red1[2] + red1[3]) * (1.0f / N_EMBD);
    float ms   = (red2[0] + red2[1] + red2[2] + red2[3]) * (1.0f / N_EMBD);
    float rs = rsqrtf(ms - mean * mean + EPS);
    u16* orow = out + (size_t)row * N_EMBD;
    orow[tid]       = f2bf((v0 - mean) * rs * g[tid]       + b[tid]);
    orow[tid + 256] = f2bf((v1 - mean) * rs * g[tid + 256] + b[tid + 256]);
    orow[tid + 512] = f2bf((v2 - mean) * rs * g[tid + 512] + b[tid + 512]);
}

// ---------------- bf16 MFMA GEMM: C[M,N] = A[M,K] @ Bt[N,K]^T + bias (+epilogue) -------
// MODE 0: out bf16 = acc + bias ; MODE 1: out bf16 = gelu(acc + bias)
// MODE 2: out fp32 = acc + bias + res
template <int MODE>
__global__ __launch_bounds__(256) void gemm_bf16(const u16* __restrict__ A,
                                                 const u16* __restrict__ Bt,
                                                 const float* __restrict__ bias,
                                                 const float* __restrict__ res,
                                                 void* __restrict__ outp,
                                                 int M, int N, int K) {
    __shared__ u16 As[128][64];  // linear: global_load_lds dest (no pad allowed, m173)
    __shared__ u16 Bs[128][64];
    int tid = threadIdx.x;
    int l = tid & 63, w = tid >> 6;
    int lr = l & 15, lg = l >> 4;
    int bm = blockIdx.y * 128, bn = blockIdx.x * 128;
    int wr = (w >> 1) * 64, wc = (w & 1) * 64;
    int srow = l >> 3;           // row within 8-row chunk
    int scol = (l & 7) * 8;      // u16 col
    f32x4 acc[4][4] = {};
    for (int k0 = 0; k0 < K; k0 += 64) {
        __syncthreads();
#pragma unroll
        for (int i = 0; i < 4; i++) {
            int c = i * 4 + w;   // chunk 0..15, 8 rows each; wave-uniform LDS base
            int row = c * 8 + srow;
            GLDS(A  + (size_t)(bm + row) * K + k0 + scol, &As[c * 8][0]);
            GLDS(Bt + (size_t)(bn + row) * K + k0 + scol, &Bs[c * 8][0]);
        }
        __syncthreads();  // compiler emits vmcnt(0) drain -> glds data landed
#pragma unroll
        for (int kk = 0; kk < 2; kk++) {
            s16x8 af[4], bf[4];
#pragma unroll
            for (int i = 0; i < 4; i++) {
                af[i] = *(const s16x8*)&As[wr + i * 16 + lr][kk * 32 + lg * 8];
                bf[i] = *(const s16x8*)&Bs[wc + i * 16 + lr][kk * 32 + lg * 8];
            }
#pragma unroll
            for (int mi = 0; mi < 4; mi++)
#pragma unroll
                for (int nj = 0; nj < 4; nj++)
                    acc[mi][nj] = __builtin_amdgcn_mfma_f32_16x16x32_bf16(
                        af[mi], bf[nj], acc[mi][nj], 0, 0, 0);
        }
    }
#pragma unroll
    for (int mi = 0; mi < 4; mi++)
#pragma unroll
        for (int nj = 0; nj < 4; nj++)
#pragma unroll
            for (int r = 0; r < 4; r++) {
                int row = bm + wr + mi * 16 + lg * 4 + r;
                int col = bn + wc + nj * 16 + lr;
                float v = acc[mi][nj][r] + bias[col];
                if (MODE == 1) {
                    float u = v + 0.044715f * v * v * v;
                    v = 0.5f * v * (1.0f + tanhf(0.7978845608028654f * u));
                }
                if (MODE == 2) {
                    v += res[(size_t)row * N + col];
                    ((float*)outp)[(size_t)row * N + col] = v;
                } else {
                    ((u16*)outp)[(size_t)row * N + col] = f2bf(v);
                }
            }
}

// ---------------- flash attention, bf16 MFMA, causal, UNSCALED ----------------
// qkv bf16 [B,T,3C]; butterfly: block handles q-tiles {bx, 7-bx} (constant work)
#define QBLK 128
#define SBLK 64
__global__ __launch_bounds__(256) void attn_mfma(const u16* __restrict__ qkv,
                                                 u16* __restrict__ outp) {
    __shared__ u16 Kl[SBLK][64];   // linear (glds dest); 16-way read conflict accepted
    __shared__ u16 Vt[HD][72];     // V^T, pitch 72 + XOR swizzle on s-group
    __shared__ u16 Pl[4][32][72];  // per-wave P tile
    int tid = threadIdx.x;
    int w = tid >> 6, l = tid & 63;
    int lr = l & 15, lg = l >> 4;
    int h = blockIdx.y, b = blockIdx.z;
    size_t bbase = (size_t)b * T_SEQ * (3 * N_EMBD);

    for (int half = 0; half < 2; half++) {
        int qt = half == 0 ? blockIdx.x : 7 - blockIdx.x;
        int q0 = qt * QBLK;

        s16x8 qf[2][2];
#pragma unroll
        for (int rg = 0; rg < 2; rg++)
#pragma unroll
            for (int kk = 0; kk < 2; kk++) {
                int row = q0 + w * 32 + rg * 16 + lr;
                qf[rg][kk] = *(const s16x8*)(qkv + bbase + (size_t)row * (3 * N_EMBD) +
                                             h * HD + kk * 32 + lg * 8);
            }
        f32x4 oacc[2][4] = {};
        float mrun[2][4], lrun[2][4];
#pragma unroll
        for (int rg = 0; rg < 2; rg++)
#pragma unroll
            for (int r = 0; r < 4; r++) { mrun[rg][r] = -1e30f; lrun[rg][r] = 0.f; }

        int nt = 2 * qt + 2;
        for (int st = 0; st < nt; st++) {
            int s0 = st * SBLK;
            // ---- stage K via global_load_lds (2 calls/wave, wave-uniform dest) ----
#pragma unroll
            for (int i = 0; i < 2; i++) {
                int c = i * 4 + w;
                int row = c * 8 + (l >> 3);
                GLDS(qkv + bbase + (size_t)(s0 + row) * (3 * N_EMBD) + N_EMBD + h * HD + (l & 7) * 8,
                     &Kl[c * 8][0]);
            }
            // ---- stage V^T (reg transpose, XOR-swizzled scalar stores: 2-way = free) ----
#pragma unroll
            for (int i = 0; i < 2; i++) {
                int c = i * 256 + tid;
                int sr = c >> 3, d0 = (c & 7) * 8;
                u16x8 vv = *(const u16x8*)(qkv + bbase + (size_t)(s0 + sr) * (3 * N_EMBD) +
                                           2 * N_EMBD + h * HD + d0);
                int sz = ((sr >> 3) ^ (d0 >> 3)) * 8 + (sr & 7);
#pragma unroll
                for (int j = 0; j < 8; j++) Vt[d0 + j][sz] = vv[j];
            }
            __syncthreads();
            // ---- S = Q @ K^T ----
            f32x4 sacc[2][4] = {};
#pragma unroll
            for (int kk = 0; kk < 2; kk++) {
                s16x8 kf[4];
#pragma unroll
                for (int nj = 0; nj < 4; nj++)
                    kf[nj] = *(const s16x8*)&Kl[nj * 16 + lr][kk * 32 + lg * 8];
#pragma unroll
                for (int rg = 0; rg < 2; rg++)
#pragma unroll
                    for (int nj = 0; nj < 4; nj++)
                        sacc[rg][nj] = __builtin_amdgcn_mfma_f32_16x16x32_bf16(
                            qf[rg][kk], kf[nj], sacc[rg][nj], 0, 0, 0);
            }
            // ---- mask + online softmax (fp32) + P -> LDS (bf16) ----
#pragma unroll
            for (int rg = 0; rg < 2; rg++) {
                int qrow0 = q0 + w * 32 + rg * 16 + lg * 4;
                float mx[4];
#pragma unroll
                for (int r = 0; r < 4; r++) {
                    int qi = qrow0 + r;
                    float mv = -1e30f;
#pragma unroll
                    for (int nj = 0; nj < 4; nj++) {
                        int si = s0 + nj * 16 + lr;
                        float v = sacc[rg][nj][r];
                        v = (si <= qi) ? v : -1e30f;
                        sacc[rg][nj][r] = v;
                        mv = fmaxf(mv, v);
                    }
                    mx[r] = mv;
                }
#pragma unroll
                for (int d = 1; d < 16; d <<= 1)
#pragma unroll
                    for (int r = 0; r < 4; r++) mx[r] = fmaxf(mx[r], __shfl_xor(mx[r], d, 64));
                float rs[4];
#pragma unroll
                for (int r = 0; r < 4; r++) {
                    float mnew = fmaxf(mrun[rg][r], mx[r]);
                    float sc = __expf(mrun[rg][r] - mnew);
                    mrun[rg][r] = mnew;
                    float sum = 0.f;
#pragma unroll
                    for (int nj = 0; nj < 4; nj++) {
                        float p = __expf(sacc[rg][nj][r] - mnew);
                        sacc[rg][nj][r] = p;
                        sum += p;
                    }
                    rs[r] = sum;
                    lrun[rg][r] *= sc;
#pragma unroll
                    for (int nj = 0; nj < 4; nj++) oacc[rg][nj][r] *= sc;
                }
#pragma unroll
                for (int d = 1; d < 16; d <<= 1)
#pragma unroll
                    for (int r = 0; r < 4; r++) rs[r] += __shfl_xor(rs[r], d, 64);
#pragma unroll
                for (int r = 0; r < 4; r++) lrun[rg][r] += rs[r];
#pragma unroll
                for (int nj = 0; nj < 4; nj++)
#pragma unroll
                    for (int r = 0; r < 4; r++)
                        Pl[w][rg * 16 + lg * 4 + r][nj * 16 + lr] = f2bf(sacc[rg][nj][r]);
            }
            __syncthreads();
            // ---- O += P @ V  (V^T read back through the same XOR swizzle) ----
#pragma unroll
            for (int kk = 0; kk < 2; kk++) {
                s16x8 af[2], vf[4];
#pragma unroll
                for (int rg = 0; rg < 2; rg++)
                    af[rg] = *(const s16x8*)&Pl[w][rg * 16 + lr][kk * 32 + lg * 8];
#pragma unroll
                for (int nj = 0; nj < 4; nj++) {
                    int d = nj * 16 + lr;
                    int gs = (kk * 4 + lg) ^ (d >> 3);
                    vf[nj] = *(const s16x8*)&Vt[d][gs * 8];
                }
#pragma unroll
                for (int rg = 0; rg < 2; rg++)
#pragma unroll
                    for (int nj = 0; nj < 4; nj++)
                        oacc[rg][nj] = __builtin_amdgcn_mfma_f32_16x16x32_bf16(
                            af[rg], vf[nj], oacc[rg][nj], 0, 0, 0);
            }
            __syncthreads();
        }
        // ---- write O/l as bf16 ----
#pragma unroll
        for (int rg = 0; rg < 2; rg++)
#pragma unroll
            for (int nj = 0; nj < 4; nj++)
#pragma unroll
                for (int r = 0; r < 4; r++) {
                    int row = q0 + w * 32 + rg * 16 + lg * 4 + r;
                    float v = oacc[rg][nj][r] / lrun[rg][r];
                    outp[(size_t)(b * T_SEQ + row) * N_EMBD + h * HD + nj * 16 + lr] = f2bf(v);
                }
    }
}

extern "C" void kernel_launch(void* const* d_in, const int* in_sizes, int n_in,
                              void* d_out, int out_size, void* d_ws, size_t ws_size,
                              hipStream_t stream) {
    (void)in_sizes; (void)n_in; (void)out_size; (void)ws_size;
    const float* x      = (const float*)d_in[0];
    const float* ln1_g  = (const float*)d_in[1];
    const float* ln1_b  = (const float*)d_in[2];
    const float* w_attn = (const float*)d_in[3];
    const float* b_attn = (const float*)d_in[4];
    const float* w_proj = (const float*)d_in[5];
    const float* b_proj = (const float*)d_in[6];
    const float* ln2_g  = (const float*)d_in[7];
    const float* ln2_b  = (const float*)d_in[8];
    const float* w_fc   = (const float*)d_in[9];
    const float* b_fc   = (const float*)d_in[10];
    const float* w_fc2  = (const float*)d_in[11];
    const float* b_fc2  = (const float*)d_in[12];
    float* out = (float*)d_out;
    u16* ws = (u16*)d_ws;

    u16* wTa  = ws;                                      // [2304,768]
    u16* wTp  = wTa + (size_t)2304 * 768;                // [768,768]
    u16* wTf  = wTp + (size_t)768 * 768;                 // [3072,768]
    u16* wTf2 = wTf + (size_t)3072 * 768;                // [768,3072]
    u16* hbuf = wTf2 + (size_t)768 * 3072;               // [8192,768]
    u16* abuf = hbuf + (size_t)M_TOK * N_EMBD;           // [8192,768]
    u16* big  = abuf + (size_t)M_TOK * N_EMBD;           // [8192,2304] / [8192,3072]

    wconv<<<dim3(2304 / 64, 768 / 64), 256, 0, stream>>>(w_attn, wTa, 768, 2304);
    wconv<<<dim3(768 / 64, 768 / 64), 256, 0, stream>>>(w_proj, wTp, 768, 768);
    wconv<<<dim3(3072 / 64, 768 / 64), 256, 0, stream>>>(w_fc, wTf, 768, 3072);
    wconv<<<dim3(768 / 64, 3072 / 64), 256, 0, stream>>>(w_fc2, wTf2, 3072, 768);
    ln_bf16<<<M_TOK, 256, 0, stream>>>(x, ln1_g, ln1_b, hbuf);
    gemm_bf16<0><<<dim3(18, 64), 256, 0, stream>>>(hbuf, wTa, b_attn, nullptr, big,
                                                   M_TOK, 3 * N_EMBD, N_EMBD);
    attn_mfma<<<dim3(T_SEQ / QBLK / 2, NHEAD, BATCH), 256, 0, stream>>>(big, abuf);
    gemm_bf16<2><<<dim3(6, 64), 256, 0, stream>>>(abuf, wTp, b_proj, x, out,
                                                  M_TOK, N_EMBD, N_EMBD);
    ln_bf16<<<M_TOK, 256, 0, stream>>>(out, ln2_g, ln2_b, hbuf);
    gemm_bf16<1><<<dim3(24, 64), 256, 0, stream>>>(hbuf, wTf, b_fc, nullptr, big,
                                                   M_TOK, 4 * N_EMBD, N_EMBD);
    gemm_bf16<2><<<dim3(6, 64), 256, 0, stream>>>(big, wTf2, b_fc2, out, out,
                                                  M_TOK, N_EMBD, 4 * N_EMBD);
}

// Round 5
// 439.656 us; speedup vs baseline: 14.3607x; 1.0384x over previous
//
#include <hip/hip_runtime.h>
#include <math.h>

#define N_EMBD 768
#define T_SEQ  1024
#define BATCH  8
#define NHEAD  12
#define HD     64
#define EPS    1e-5f
#define M_TOK  (BATCH * T_SEQ)   // 8192

typedef unsigned short u16;
typedef __attribute__((ext_vector_type(8))) short          s16x8;
typedef __attribute__((ext_vector_type(8))) unsigned short u16x8;
typedef __attribute__((ext_vector_type(4))) float          f32x4;

#define GLDS(gp, lp) \
    __builtin_amdgcn_global_load_lds( \
        (const __attribute__((address_space(1))) void*)(gp), \
        (__attribute__((address_space(3))) void*)(lp), 16, 0, 0)

__device__ __forceinline__ u16 f2bf(float f) {
    unsigned int u = __float_as_uint(f);
    u += 0x7fffu + ((u >> 16) & 1u);
    return (u16)(u >> 16);
}

// ---------------- weight convert + transpose: fp32 [R][C] -> bf16 [C][R] ----------------
__global__ __launch_bounds__(256) void wconv(const float* __restrict__ in,
                                             u16* __restrict__ out, int R, int C) {
    __shared__ float tile[64][65];
    int t = threadIdx.x;
    int r0 = blockIdx.y * 64, c0 = blockIdx.x * 64;
    int rl = t >> 4, c4 = (t & 15) * 4;
#pragma unroll
    for (int i = 0; i < 4; i++) {
        float4 v = *(const float4*)(in + (size_t)(r0 + rl + i * 16) * C + c0 + c4);
        tile[rl + i * 16][c4 + 0] = v.x;
        tile[rl + i * 16][c4 + 1] = v.y;
        tile[rl + i * 16][c4 + 2] = v.z;
        tile[rl + i * 16][c4 + 3] = v.w;
    }
    __syncthreads();
#pragma unroll
    for (int i = 0; i < 4; i++) {
        int crow = rl + i * 16;
        ushort4 s4;
        s4.x = f2bf(tile[c4 + 0][crow]);
        s4.y = f2bf(tile[c4 + 1][crow]);
        s4.z = f2bf(tile[c4 + 2][crow]);
        s4.w = f2bf(tile[c4 + 3][crow]);
        *(ushort4*)(out + (size_t)(c0 + crow) * R + r0 + c4) = s4;
    }
}

// ---------------- LayerNorm fp32 in -> bf16 out ----------------
__global__ __launch_bounds__(256) void ln_bf16(const float* __restrict__ x,
                                               const float* __restrict__ g,
                                               const float* __restrict__ b,
                                               u16* __restrict__ out) {
    int row = blockIdx.x;
    int tid = threadIdx.x;
    const float* xr = x + (size_t)row * N_EMBD;
    float v0 = xr[tid], v1 = xr[tid + 256], v2 = xr[tid + 512];
    float s1 = v0 + v1 + v2;
    float s2 = v0 * v0 + v1 * v1 + v2 * v2;
    __shared__ float red1[4], red2[4];
#pragma unroll
    for (int o = 32; o > 0; o >>= 1) {
        s1 += __shfl_down(s1, o);
        s2 += __shfl_down(s2, o);
    }
    if ((tid & 63) == 0) { red1[tid >> 6] = s1; red2[tid >> 6] = s2; }
    __syncthreads();
    float mean = (red1[0] + red1[1] + red1[2] + red1[3]) * (1.0f / N_EMBD);
    float ms   = (red2[0] + red2[1] + red2[2] + red2[3]) * (1.0f / N_EMBD);
    float rs = rsqrtf(ms - mean * mean + EPS);
    u16* orow = out + (size_t)row * N_EMBD;
    orow[tid]       = f2bf((v0 - mean) * rs * g[tid]       + b[tid]);
    orow[tid + 256] = f2bf((v1 - mean) * rs * g[tid + 256] + b[tid + 256]);
    orow[tid + 512] = f2bf((v2 - mean) * rs * g[tid + 512] + b[tid + 512]);
}

// ---------------- bf16 MFMA GEMM, double-buffered prefetch (T3-minimum) ----------------
// C[M,N] = A[M,K] @ Bt[N,K]^T + bias; MODE 0: bf16 out; 1: bf16 gelu; 2: fp32 +res
template <int MODE>
__global__ __launch_bounds__(256) void gemm_bf16(const u16* __restrict__ A,
                                                 const u16* __restrict__ Bt,
                                                 const float* __restrict__ bias,
                                                 const float* __restrict__ res,
                                                 void* __restrict__ outp,
                                                 int M, int N, int K) {
    __shared__ u16 As[2][128][64];  // linear: glds dest (64KB total with Bs)
    __shared__ u16 Bs[2][128][64];
    int tid = threadIdx.x;
    int l = tid & 63, w = tid >> 6;
    int lr = l & 15, lg = l >> 4;
    // bijective XCD swizzle (all grids are %8==0)
    int gx = gridDim.x, nwg = gx * gridDim.y;
    int bid = blockIdx.y * gx + blockIdx.x;
    int swz = (bid & 7) * (nwg >> 3) + (bid >> 3);
    int bm = (swz / gx) * 128, bn = (swz % gx) * 128;
    int wr = (w >> 1) * 64, wc = (w & 1) * 64;
    int srow = l >> 3, scol = (l & 7) * 8;
    f32x4 acc[4][4] = {};
    int nt = K / 64;
    // prologue: stage tile 0
#pragma unroll
    for (int i = 0; i < 4; i++) {
        int c = i * 4 + w;
        int row = c * 8 + srow;
        GLDS(A  + (size_t)(bm + row) * K + scol, &As[0][c * 8][0]);
        GLDS(Bt + (size_t)(bn + row) * K + scol, &Bs[0][c * 8][0]);
    }
    int cur = 0;
    for (int t = 0; t < nt; t++) {
        __syncthreads();  // drains vmcnt: buf[cur] (issued last iter, flew under MFMA)
        if (t + 1 < nt) {
            int k0 = (t + 1) * 64;
#pragma unroll
            for (int i = 0; i < 4; i++) {
                int c = i * 4 + w;
                int row = c * 8 + srow;
                GLDS(A  + (size_t)(bm + row) * K + k0 + scol, &As[cur ^ 1][c * 8][0]);
                GLDS(Bt + (size_t)(bn + row) * K + k0 + scol, &Bs[cur ^ 1][c * 8][0]);
            }
        }
#pragma unroll
        for (int kk = 0; kk < 2; kk++) {
            s16x8 af[4], bf[4];
#pragma unroll
            for (int i = 0; i < 4; i++) {
                af[i] = *(const s16x8*)&As[cur][wr + i * 16 + lr][kk * 32 + lg * 8];
                bf[i] = *(const s16x8*)&Bs[cur][wc + i * 16 + lr][kk * 32 + lg * 8];
            }
#pragma unroll
            for (int mi = 0; mi < 4; mi++)
#pragma unroll
                for (int nj = 0; nj < 4; nj++)
                    acc[mi][nj] = __builtin_amdgcn_mfma_f32_16x16x32_bf16(
                        af[mi], bf[nj], acc[mi][nj], 0, 0, 0);
        }
        cur ^= 1;
    }
#pragma unroll
    for (int mi = 0; mi < 4; mi++)
#pragma unroll
        for (int nj = 0; nj < 4; nj++)
#pragma unroll
            for (int r = 0; r < 4; r++) {
                int row = bm + wr + mi * 16 + lg * 4 + r;
                int col = bn + wc + nj * 16 + lr;
                float v = acc[mi][nj][r] + bias[col];
                if (MODE == 1) {
                    // gelu-tanh via exp (saturation-safe): v - v/(1+e^{2u})
                    float u = 1.5957691216057308f * (v + 0.044715f * v * v * v);
                    v = v - v / (1.0f + __expf(u));
                }
                if (MODE == 2) {
                    v += res[(size_t)row * N + col];
                    ((float*)outp)[(size_t)row * N + col] = v;
                } else {
                    ((u16*)outp)[(size_t)row * N + col] = f2bf(v);
                }
            }
}

// ---------------- flash attention, bf16 MFMA, causal, UNSCALED (round-4, unchanged) ----
#define QBLK 128
#define SBLK 64
__global__ __launch_bounds__(256) void attn_mfma(const u16* __restrict__ qkv,
                                                 u16* __restrict__ outp) {
    __shared__ u16 Kl[SBLK][64];
    __shared__ u16 Vt[HD][72];
    __shared__ u16 Pl[4][32][72];
    int tid = threadIdx.x;
    int w = tid >> 6, l = tid & 63;
    int lr = l & 15, lg = l >> 4;
    int h = blockIdx.y, b = blockIdx.z;
    size_t bbase = (size_t)b * T_SEQ * (3 * N_EMBD);

    for (int half = 0; half < 2; half++) {
        int qt = half == 0 ? blockIdx.x : 7 - blockIdx.x;
        int q0 = qt * QBLK;
        s16x8 qf[2][2];
#pragma unroll
        for (int rg = 0; rg < 2; rg++)
#pragma unroll
            for (int kk = 0; kk < 2; kk++) {
                int row = q0 + w * 32 + rg * 16 + lr;
                qf[rg][kk] = *(const s16x8*)(qkv + bbase + (size_t)row * (3 * N_EMBD) +
                                             h * HD + kk * 32 + lg * 8);
            }
        f32x4 oacc[2][4] = {};
        float mrun[2][4], lrun[2][4];
#pragma unroll
        for (int rg = 0; rg < 2; rg++)
#pragma unroll
            for (int r = 0; r < 4; r++) { mrun[rg][r] = -1e30f; lrun[rg][r] = 0.f; }

        int nt = 2 * qt + 2;
        for (int st = 0; st < nt; st++) {
            int s0 = st * SBLK;
#pragma unroll
            for (int i = 0; i < 2; i++) {
                int c = i * 4 + w;
                int row = c * 8 + (l >> 3);
                GLDS(qkv + bbase + (size_t)(s0 + row) * (3 * N_EMBD) + N_EMBD + h * HD + (l & 7) * 8,
                     &Kl[c * 8][0]);
            }
#pragma unroll
            for (int i = 0; i < 2; i++) {
                int c = i * 256 + tid;
                int sr = c >> 3, d0 = (c & 7) * 8;
                u16x8 vv = *(const u16x8*)(qkv + bbase + (size_t)(s0 + sr) * (3 * N_EMBD) +
                                           2 * N_EMBD + h * HD + d0);
                int sz = ((sr >> 3) ^ (d0 >> 3)) * 8 + (sr & 7);
#pragma unroll
                for (int j = 0; j < 8; j++) Vt[d0 + j][sz] = vv[j];
            }
            __syncthreads();
            f32x4 sacc[2][4] = {};
#pragma unroll
            for (int kk = 0; kk < 2; kk++) {
                s16x8 kf[4];
#pragma unroll
                for (int nj = 0; nj < 4; nj++)
                    kf[nj] = *(const s16x8*)&Kl[nj * 16 + lr][kk * 32 + lg * 8];
#pragma unroll
                for (int rg = 0; rg < 2; rg++)
#pragma unroll
                    for (int nj = 0; nj < 4; nj++)
                        sacc[rg][nj] = __builtin_amdgcn_mfma_f32_16x16x32_bf16(
                            qf[rg][kk], kf[nj], sacc[rg][nj], 0, 0, 0);
            }
#pragma unroll
            for (int rg = 0; rg < 2; rg++) {
                int qrow0 = q0 + w * 32 + rg * 16 + lg * 4;
                float mx[4];
#pragma unroll
                for (int r = 0; r < 4; r++) {
                    int qi = qrow0 + r;
                    float mv = -1e30f;
#pragma unroll
                    for (int nj = 0; nj < 4; nj++) {
                        int si = s0 + nj * 16 + lr;
                        float v = sacc[rg][nj][r];
                        v = (si <= qi) ? v : -1e30f;
                        sacc[rg][nj][r] = v;
                        mv = fmaxf(mv, v);
                    }
                    mx[r] = mv;
                }
#pragma unroll
                for (int d = 1; d < 16; d <<= 1)
#pragma unroll
                    for (int r = 0; r < 4; r++) mx[r] = fmaxf(mx[r], __shfl_xor(mx[r], d, 64));
                float rs[4];
#pragma unroll
                for (int r = 0; r < 4; r++) {
                    float mnew = fmaxf(mrun[rg][r], mx[r]);
                    float sc = __expf(mrun[rg][r] - mnew);
                    mrun[rg][r] = mnew;
                    float sum = 0.f;
#pragma unroll
                    for (int nj = 0; nj < 4; nj++) {
                        float p = __expf(sacc[rg][nj][r] - mnew);
                        sacc[rg][nj][r] = p;
                        sum += p;
                    }
                    rs[r] = sum;
                    lrun[rg][r] *= sc;
#pragma unroll
                    for (int nj = 0; nj < 4; nj++) oacc[rg][nj][r] *= sc;
                }
#pragma unroll
                for (int d = 1; d < 16; d <<= 1)
#pragma unroll
                    for (int r = 0; r < 4; r++) rs[r] += __shfl_xor(rs[r], d, 64);
#pragma unroll
                for (int r = 0; r < 4; r++) lrun[rg][r] += rs[r];
#pragma unroll
                for (int nj = 0; nj < 4; nj++)
#pragma unroll
                    for (int r = 0; r < 4; r++)
                        Pl[w][rg * 16 + lg * 4 + r][nj * 16 + lr] = f2bf(sacc[rg][nj][r]);
            }
            __syncthreads();
#pragma unroll
            for (int kk = 0; kk < 2; kk++) {
                s16x8 af[2], vf[4];
#pragma unroll
                for (int rg = 0; rg < 2; rg++)
                    af[rg] = *(const s16x8*)&Pl[w][rg * 16 + lr][kk * 32 + lg * 8];
#pragma unroll
                for (int nj = 0; nj < 4; nj++) {
                    int d = nj * 16 + lr;
                    int gs = (kk * 4 + lg) ^ (d >> 3);
                    vf[nj] = *(const s16x8*)&Vt[d][gs * 8];
                }
#pragma unroll
                for (int rg = 0; rg < 2; rg++)
#pragma unroll
                    for (int nj = 0; nj < 4; nj++)
                        oacc[rg][nj] = __builtin_amdgcn_mfma_f32_16x16x32_bf16(
                            af[rg], vf[nj], oacc[rg][nj], 0, 0, 0);
            }
            __syncthreads();
        }
#pragma unroll
        for (int rg = 0; rg < 2; rg++)
#pragma unroll
            for (int nj = 0; nj < 4; nj++)
#pragma unroll
                for (int r = 0; r < 4; r++) {
                    int row = q0 + w * 32 + rg * 16 + lg * 4 + r;
                    float v = oacc[rg][nj][r] / lrun[rg][r];
                    outp[(size_t)(b * T_SEQ + row) * N_EMBD + h * HD + nj * 16 + lr] = f2bf(v);
                }
    }
}

extern "C" void kernel_launch(void* const* d_in, const int* in_sizes, int n_in,
                              void* d_out, int out_size, void* d_ws, size_t ws_size,
                              hipStream_t stream) {
    (void)in_sizes; (void)n_in; (void)out_size; (void)ws_size;
    const float* x      = (const float*)d_in[0];
    const float* ln1_g  = (const float*)d_in[1];
    const float* ln1_b  = (const float*)d_in[2];
    const float* w_attn = (const float*)d_in[3];
    const float* b_attn = (const float*)d_in[4];
    const float* w_proj = (const float*)d_in[5];
    const float* b_proj = (const float*)d_in[6];
    const float* ln2_g  = (const float*)d_in[7];
    const float* ln2_b  = (const float*)d_in[8];
    const float* w_fc   = (const float*)d_in[9];
    const float* b_fc   = (const float*)d_in[10];
    const float* w_fc2  = (const float*)d_in[11];
    const float* b_fc2  = (const float*)d_in[12];
    float* out = (float*)d_out;
    u16* ws = (u16*)d_ws;

    u16* wTa  = ws;                                      // [2304,768]
    u16* wTp  = wTa + (size_t)2304 * 768;                // [768,768]
    u16* wTf  = wTp + (size_t)768 * 768;                 // [3072,768]
    u16* wTf2 = wTf + (size_t)3072 * 768;                // [768,3072]
    u16* hbuf = wTf2 + (size_t)768 * 3072;               // [8192,768]
    u16* abuf = hbuf + (size_t)M_TOK * N_EMBD;           // [8192,768]
    u16* big  = abuf + (size_t)M_TOK * N_EMBD;           // [8192,2304] / [8192,3072]

    wconv<<<dim3(2304 / 64, 768 / 64), 256, 0, stream>>>(w_attn, wTa, 768, 2304);
    wconv<<<dim3(768 / 64, 768 / 64), 256, 0, stream>>>(w_proj, wTp, 768, 768);
    wconv<<<dim3(3072 / 64, 768 / 64), 256, 0, stream>>>(w_fc, wTf, 768, 3072);
    wconv<<<dim3(768 / 64, 3072 / 64), 256, 0, stream>>>(w_fc2, wTf2, 3072, 768);
    ln_bf16<<<M_TOK, 256, 0, stream>>>(x, ln1_g, ln1_b, hbuf);
    gemm_bf16<0><<<dim3(18, 64), 256, 0, stream>>>(hbuf, wTa, b_attn, nullptr, big,
                                                   M_TOK, 3 * N_EMBD, N_EMBD);
    attn_mfma<<<dim3(T_SEQ / QBLK / 2, NHEAD, BATCH), 256, 0, stream>>>(big, abuf);
    gemm_bf16<2><<<dim3(6, 64), 256, 0, stream>>>(abuf, wTp, b_proj, x, out,
                                                  M_TOK, N_EMBD, N_EMBD);
    ln_bf16<<<M_TOK, 256, 0, stream>>>(out, ln2_g, ln2_b, hbuf);
    gemm_bf16<1><<<dim3(24, 64), 256, 0, stream>>>(hbuf, wTf, b_fc, nullptr, big,
                                                   M_TOK, 4 * N_EMBD, N_EMBD);
    gemm_bf16<2><<<dim3(6, 64), 256, 0, stream>>>(big, wTf2, b_fc2, out, out,
                                                  M_TOK, N_EMBD, 4 * N_EMBD);
}